// Round 15
// baseline (140.387 us; speedup 1.0000x reference)
//
#include <hip/hip_runtime.h>
#include <math.h>

#define NB 8
#define NC 128

typedef _Float16 hf8 __attribute__((ext_vector_type(8)));
typedef _Float16 hf4 __attribute__((ext_vector_type(4)));
typedef float fx4 __attribute__((ext_vector_type(4)));

// ---------------- LUT: lut[d2] = dw * (1/(sqrt(d2)+1e-6)) (fallback only) ---
__global__ void lut_kernel(float* __restrict__ lut, const float* __restrict__ dwp,
                           int n) {
  int i = blockIdx.x * 256 + threadIdx.x;
  if (i < n) {
    float r = 1.0f / (sqrtf((float)i) + 1e-6f);
    lut[i] = dwp[0] * r;
  }
}

// ---- prep: x (B,C,4096) -> xf1, nrm1, ext1 (K=128 fp16 metric), xf2/cnt1 ---
__global__ void prep_kernel(const float* __restrict__ x, float* __restrict__ xf,
                            float* __restrict__ nrm, _Float16* __restrict__ ext,
                            float* __restrict__ xf2, float* __restrict__ cnt1) {
  __shared__ float tile[64][129];
  __shared__ float part[64][4];
  __shared__ float rn_s[64];
  const int bid = blockIdx.x;
  const int b = bid & 7;
  const int p0 = (bid >> 3) * 64;
  const int tid = threadIdx.x;
  const int lane = tid & 63;
  const int q = tid >> 6;
  for (int cc = 0; cc < 32; ++cc) {
    int c = q * 32 + cc;
    tile[lane][c] = x[((size_t)(b * NC + c)) * 4096 + p0 + lane];
  }
  __syncthreads();
  float s = 0.f;
  for (int cc = 0; cc < 32; ++cc) {
    float v = tile[lane][q * 32 + cc];
    s += v * v;
  }
  part[lane][q] = s;
  __syncthreads();
  if (tid < 64) {
    float n = sqrtf(part[tid][0] + part[tid][1] + part[tid][2] + part[tid][3]);
    nrm[b * 4096 + p0 + tid] = n;
    rn_s[tid] = n;
  }
  __syncthreads();
  for (int it = 0; it < 8; ++it) {
    int idx = it * 256 + tid;
    int r = idx >> 5, e = (idx & 31) * 4;
    float4 v = make_float4(tile[r][e], tile[r][e + 1], tile[r][e + 2], tile[r][e + 3]);
    size_t o = (((size_t)b * 4096 + p0 + r) << 7) + e;
    *(float4*)&xf[o] = v;
    int tok = p0 + r;
    if (tok >= 2048) {  // merge-1 accumulator init (replaces copy_init m1)
      size_t row2 = (size_t)b * 2048 + tok - 2048;
      *(float4*)&xf2[row2 * NC + e] = v;
      if (e == 0) cnt1[row2] = 1.0f;
    }
    if (ext != nullptr) {
      float n = rn_s[r];
      _Float16* rw = ext + ((size_t)b * 4096 + tok) * 128;
      hf4 hv = {(_Float16)(v.x / n), (_Float16)(v.y / n),
                (_Float16)(v.z / n), (_Float16)(v.w / n)};
      *(hf4*)&rw[e] = hv;
    }
  }
}

// ------ MFMA candidate kernel v10: K=128, ALL A-fragments hoisted -----------
// Block: 4 waves, each wave = 64i x 64j. LB(256,3) -> VGPR cap ~170 so the
// 16 A-fragment loads (64 VGPR) issue at kernel entry and land under the
// B-staging + barrier shadow; the kc loop is then pure LDS-read + MFMA.
// 1D grid: b = bid&7 (batch->XCD), jb = (bid>>3)&(NJB-1), ib = (bid>>3)/NJB.
// Emits packed u64 top-2 per (row, 64-j chunk).
template <int WIDTH, int TT, int HH, int NJB>
__global__ __launch_bounds__(256, 3) void argmax_mfma10_kernel(
    const _Float16* __restrict__ ext, const float* __restrict__ swp,
    const float* __restrict__ dwp, unsigned long long* __restrict__ pu) {
  // staging row stride 152 (same bank pattern as proven 280); full 64*280
  // halfs reserved so the u64 reduce reuse (34816 B) fits.
  __shared__ _Float16 Bt[64 * 280];
  const int bid = blockIdx.x;
  const int b = bid & 7;
  const int rr = bid >> 3;
  const int jb = rr & (NJB - 1);
  const int ib = rr / NJB;
  const int tid = threadIdx.x;
  const int w = tid >> 6, l = tid & 63;
  const int lg = l >> 4, lm = l & 15;
  const int ipan = ib * 256 + w * 64;
  const int j0 = jb * 64;
  const float sw = swp[0], dwv = dwp[0];
  const _Float16* extb = ext + (size_t)b * TT * 128;
  const _Float16* brow0 = extb + (size_t)(HH + j0) * 128;

  // ---- hoist: issue ALL 16 A-fragment loads now (4 i4 x 4 kc) ----
  hf8 af[4][4];
#pragma unroll
  for (int s = 0; s < 4; ++s) {
    const _Float16* ap = extb + (size_t)(ipan + s * 16 + lm) * 128 + lg * 8;
#pragma unroll
    for (int kc = 0; kc < 4; ++kc) af[s][kc] = *(const hf8*)(ap + kc * 32);
  }

  // stage B tile once: 64 rows x 128 halfs (overlaps with A loads in flight)
  for (int f = tid; f < 64 * 16; f += 256) {
    int r = f >> 4, c = f & 15;
    *(float4*)&Bt[r * 152 + c * 8] =
        *(const float4*)&brow0[(size_t)r * 128 + c * 8];
  }
  __syncthreads();

  fx4 acc[4][4];
#pragma unroll
  for (int i4 = 0; i4 < 4; ++i4)
#pragma unroll
    for (int j4 = 0; j4 < 4; ++j4) acc[i4][j4] = 0.f;

#pragma unroll
  for (int kc = 0; kc < 4; ++kc) {
    hf8 bf[4];
#pragma unroll
    for (int s = 0; s < 4; ++s)
      bf[s] = *(const hf8*)&Bt[(s * 16 + lm) * 152 + kc * 32 + lg * 8];
    __builtin_amdgcn_s_setprio(1);
#pragma unroll
    for (int j4 = 0; j4 < 4; ++j4)
#pragma unroll
      for (int i4 = 0; i4 < 4; ++i4)
        acc[i4][j4] = __builtin_amdgcn_mfma_f32_16x16x32_f16(
            af[i4][kc], bf[j4], acc[i4][j4], 0, 0, 0);
    __builtin_amdgcn_s_setprio(0);
  }

  // ---- epilogue: per-lane first-max over its 4 cols, per row ----
  // C/D layout: row = lg*4 + reg (+i4*16), col = lm (+j4*16).
  int jr4[4], jc4[4];
#pragma unroll
  for (int j4 = 0; j4 < 4; ++j4) {
    int tj = HH + j0 + j4 * 16 + lm;
    jr4[j4] = tj / WIDTH;
    jc4[j4] = tj % WIDTH;
  }
  __syncthreads();  // all waves done reading Bt -> reuse as reduce buffer
  unsigned long long* rwv = (unsigned long long*)&Bt[0] + (size_t)w * 64 * 17;
#pragma unroll
  for (int i4 = 0; i4 < 4; ++i4) {
#pragma unroll
    for (int rg = 0; rg < 4; ++rg) {
      int il = i4 * 16 + lg * 4 + rg;
      int ti = ipan + il;
      int ir = ti / WIDTH, ic = ti % WIDTH;
      float bv = -1e30f;
      int bj = 0;
#pragma unroll
      for (int j4 = 0; j4 < 4; ++j4) {  // ascending j -> first-max kept
        int dr = ir - jr4[j4], dc = ic - jc4[j4];
        float d2 = (float)(dr * dr + dc * dc);
        float sc = sw * acc[i4][j4][rg] + dwv * __builtin_amdgcn_rsqf(d2);
        int gj = j0 + j4 * 16 + lm;
        if (sc > bv) { bv = sc; bj = gj; }
      }
      rwv[il * 17 + lm] =
          ((unsigned long long)__float_as_uint(bv + 1.0f) << 32) |
          (unsigned)(~(unsigned)bj);
    }
  }
  __syncthreads();
  // lane l owns row l: top-2 over 16 lane-maxima (u64 packed order)
  unsigned long long t1 = 0ull, t2 = 0ull;
#pragma unroll
  for (int c = 0; c < 16; ++c) {
    unsigned long long u = rwv[l * 17 + c];
    if (u > t1) { t2 = t1; t1 = u; }
    else if (u > t2) { t2 = u; }
  }
  size_t row = (size_t)b * HH + ipan + l;
  pu[row * (HH / 32) + jb * 2 + 0] = t1;
  pu[row * (HH / 32) + jb * 2 + 1] = t2;
}

// --- fused top-4 + exact fp32 refine + SCATTER: one wave per row ------------
template <int WIDTH, int TT, int HH, int NCH2>
__global__ __launch_bounds__(256) void tkrscat_kernel(
    const unsigned long long* __restrict__ pu, const float* __restrict__ xf,
    const float* __restrict__ nrm, const float* __restrict__ swp,
    const float* __restrict__ dwp, float* __restrict__ accbuf,
    float* __restrict__ cnt) {
  const int bid = blockIdx.x;
  const int bb = bid & 7;
  const int row = bb * HH + (bid >> 3) * 4 + (threadIdx.x >> 6);
  const int lane = threadIdx.x & 63;
  unsigned long long v = (lane < NCH2) ? pu[(size_t)row * NCH2 + lane] : 0ull;
  int candv[4];
#pragma unroll
  for (int t = 0; t < 4; ++t) {
    unsigned long long m = v;
#pragma unroll
    for (int off = 1; off < 64; off <<= 1) {
      unsigned long long o = __shfl_xor(m, off, 64);
      if (o > m) m = o;
    }
    candv[t] = (int)(~(unsigned)(m & 0xFFFFFFFFull));
    if (v == m) v = 0ull;  // packed u64 unique per j -> exact removal
  }
  const int half = lane >> 5, ln = lane & 31;
  const int b = row / HH, i = row - b * HH;
  const float sw = swp[0], dwv = dwp[0];
  const float na = nrm[b * TT + i];
  float4 araw = *(const float4*)&xf[((size_t)b * TT + i) * NC + ln * 4];
  float4 a4 = make_float4(araw.x / na, araw.y / na, araw.z / na, araw.w / na);
  const int ir = i / WIDTH, ic = i % WIDTH;
  float bv = -3.0e38f;
  int bj = 0x7fffffff;
#pragma unroll
  for (int c = 0; c < 4; c += 2) {
    int j = candv[c + half];
    float4 b4 = *(const float4*)&xf[((size_t)b * TT + HH + j) * NC + ln * 4];
    float p = a4.x * b4.x + a4.y * b4.y + a4.z * b4.z + a4.w * b4.w;
#pragma unroll
    for (int off = 1; off < 32; off <<= 1) p += __shfl_xor(p, off, 32);
    float nb = nrm[b * TT + HH + j];
    int tj = HH + j;
    int jr = tj / WIDTH;
    int dr = ir - jr, dc = ic - (tj - jr * WIDTH);
    float r = 1.0f / (sqrtf((float)(dr * dr + dc * dc)) + 1e-6f);
    float sc = sw * (p / nb) + dwv * r;
    if (sc > bv || (sc == bv && j < bj)) { bv = sc; bj = j; }
  }
  {
    float ov = __shfl_xor(bv, 32, 64);
    int oj = __shfl_xor(bj, 32, 64);
    if (ov > bv || (ov == bv && oj < bj)) { bv = ov; bj = oj; }
  }
  if (half == 0) {
    float* base = &accbuf[((size_t)b * HH + bj) * NC + ln * 4];
    atomicAdd(base + 0, araw.x);
    atomicAdd(base + 1, araw.y);
    atomicAdd(base + 2, araw.z);
    atomicAdd(base + 3, araw.w);
    if (ln == 0) atomicAdd(&cnt[(size_t)b * HH + bj], 1.0f);
  }
}

// ---------------- FALLBACK fp32 path (round-1 structure, proven) ------------
template <int WIDTH, int TT, int HH, int IT, int JC>
__global__ __launch_bounds__(256, 4) void argmax2_kernel(
    const float* __restrict__ xf, const float* __restrict__ nrm,
    const float* __restrict__ swp, const float* __restrict__ lut,
    float* __restrict__ pval, int* __restrict__ pidx) {
  constexpr int MI = IT / 16;
  constexpr int NTILE = JC / 128;
  __shared__ float At[32][IT + 4];
  __shared__ float Bt[32][132];
  __shared__ int ico[2][IT];
  __shared__ int jco[2][JC];

  const int b = blockIdx.z;
  const int it0 = blockIdx.x * IT;
  const int jb = blockIdx.y;
  const int j0g = jb * JC;
  const int tid = threadIdx.x;

  for (int t = tid; t < IT; t += 256) {
    int tok = it0 + t;
    ico[0][t] = tok / WIDTH;
    ico[1][t] = tok % WIDTH;
  }
  for (int t = tid; t < JC; t += 256) {
    int tok = HH + j0g + t;
    jco[0][t] = tok / WIDTH;
    jco[1][t] = tok % WIDTH;
  }
  const float sw = swp[0];
  const float* srcb = xf + (size_t)b * TT * NC;

  const int ty = tid >> 4, tx = tid & 15;
  const int i0l = ty * MI;
  const int j0l = tx * 8;

  float best[MI];
  int bidx[MI];
#pragma unroll
  for (int ii = 0; ii < MI; ++ii) { best[ii] = -1e30f; bidx[ii] = 0; }

  for (int jt = 0; jt < NTILE; ++jt) {
    float acc[MI][8];
#pragma unroll
    for (int ii = 0; ii < MI; ++ii)
#pragma unroll
      for (int jj = 0; jj < 8; ++jj) acc[ii][jj] = 0.f;

    for (int kc = 0; kc < 4; ++kc) {
      __syncthreads();
#pragma unroll
      for (int p = 0; p < IT / 32; ++p) {
        int f = p * 256 + tid;
        int r = f >> 3, kq = (f & 7) * 4;
        const float* row = srcb + (size_t)(it0 + r) * NC + kc * 32 + kq;
        float4 v = *(const float4*)row;
        float n = nrm[b * TT + it0 + r];
        v.x /= n; v.y /= n; v.z /= n; v.w /= n;
        At[kq + 0][r] = v.x; At[kq + 1][r] = v.y;
        At[kq + 2][r] = v.z; At[kq + 3][r] = v.w;
      }
#pragma unroll
      for (int p = 0; p < 4; ++p) {
        int f = p * 256 + tid;
        int r = f >> 3, kq = (f & 7) * 4;
        int tok = HH + j0g + jt * 128 + r;
        const float* row = srcb + (size_t)tok * NC + kc * 32 + kq;
        float4 v = *(const float4*)row;
        float n = nrm[b * TT + tok];
        v.x /= n; v.y /= n; v.z /= n; v.w /= n;
        Bt[kq + 0][r] = v.x; Bt[kq + 1][r] = v.y;
        Bt[kq + 2][r] = v.z; Bt[kq + 3][r] = v.w;
      }
      __syncthreads();

#pragma unroll 4
      for (int k = 0; k < 32; ++k) {
        float a[MI], bb[8];
#pragma unroll
        for (int qv = 0; qv < MI / 4; ++qv)
          *(float4*)&a[qv * 4] = *(const float4*)&At[k][i0l + qv * 4];
        *(float4*)&bb[0] = *(const float4*)&Bt[k][j0l];
        *(float4*)&bb[4] = *(const float4*)&Bt[k][j0l + 4];
#pragma unroll
        for (int ii = 0; ii < MI; ++ii)
#pragma unroll
          for (int jj = 0; jj < 8; ++jj) acc[ii][jj] += a[ii] * bb[jj];
      }
    }

#pragma unroll
    for (int ii = 0; ii < MI; ++ii) {
      int ir = ico[0][i0l + ii], ic = ico[1][i0l + ii];
#pragma unroll
      for (int jj = 0; jj < 8; ++jj) {
        int jl = jt * 128 + j0l + jj;
        int dr = ir - jco[0][jl];
        int dc = ic - jco[1][jl];
        float sc = sw * acc[ii][jj] + lut[dr * dr + dc * dc];
        if (sc > best[ii]) {
          best[ii] = sc;
          bidx[ii] = j0g + jl;
        }
      }
    }
  }

  __syncthreads();
  float* rv = &At[0][0];
  int* rj = (int*)&Bt[0][0];
#pragma unroll
  for (int ii = 0; ii < MI; ++ii) {
    rv[(i0l + ii) * 17 + tx] = best[ii];
    rj[(i0l + ii) * 17 + tx] = bidx[ii];
  }
  __syncthreads();
  if (tid < IT) {
    float bv = rv[tid * 17];
    int bj = rj[tid * 17];
    for (int t = 1; t < 16; ++t) {
      float v = rv[tid * 17 + t];
      int j = rj[tid * 17 + t];
      if (v > bv || (v == bv && j < bj)) { bv = v; bj = j; }
    }
    int row = b * HH + it0 + tid;
    pval[(size_t)row * 8 + jb] = bv;
    pidx[(size_t)row * 8 + jb] = bj;
  }
}

__global__ void argreduce_kernel(const float* __restrict__ pv,
                                 const int* __restrict__ pj,
                                 int* __restrict__ dst, int nrows, int w) {
  int r = blockIdx.x * 256 + threadIdx.x;
  if (r >= nrows) return;
  const float* vv = pv + (size_t)r * w;
  const int* jj = pj + (size_t)r * w;
  float bv = vv[0];
  int bj = jj[0];
  for (int t = 1; t < w; ++t) {
    float v = vv[t];
    int j = jj[t];
    if (v > bv || (v == bv && j < bj)) { bv = v; bj = j; }
  }
  dst[r] = bj;
}

// fallback scatter (uses precomputed dst)
__global__ void scatter_kernel(const float* __restrict__ src,
                               const int* __restrict__ dst,
                               float* __restrict__ accbuf,
                               float* __restrict__ cnt, int HH, int TT) {
  const int b = blockIdx.x & 7;
  size_t local = (size_t)(blockIdx.x >> 3) * 256 + threadIdx.x;
  if (local >= (size_t)HH * 32) return;
  int i = (int)(local >> 5);
  int e = (int)(local & 31) * 4;
  float4 v = *(const float4*)&src[((size_t)b * TT + i) * NC + e];
  int d = dst[(size_t)b * HH + i];
  float* base = &accbuf[((size_t)b * HH + d) * NC + e];
  atomicAdd(base + 0, v.x);
  atomicAdd(base + 1, v.y);
  atomicAdd(base + 2, v.z);
  atomicAdd(base + 3, v.w);
  if (e == 0) atomicAdd(&cnt[(size_t)b * HH + d], 1.0f);
}

// finalize merge-1: divide xf2 by cnt1, emit nrm2 (+ ext2 fp16 metric rows),
// AND init merge-2 accumulator: b-half rows (t>=1024) copied to xf3, cnt2=1.
__global__ void finalize1_kernel(float* __restrict__ buf,
                                 const float* __restrict__ cnt,
                                 float* __restrict__ nrm,
                                 _Float16* __restrict__ ext,
                                 float* __restrict__ xf3,
                                 float* __restrict__ cnt2) {
  const int b = blockIdx.x & 7;
  int row = b * 2048 + (blockIdx.x >> 3) * 2 + (threadIdx.x >> 7);
  int c = threadIdx.x & 127;
  float v = buf[(size_t)row * NC + c] / cnt[row];
  buf[(size_t)row * NC + c] = v;
  int t = row & 2047;
  if (t >= 1024) {  // merge-2 accumulator init (replaces copy_init m2)
    size_t r3 = (size_t)b * 1024 + t - 1024;
    xf3[r3 * NC + c] = v;
    if (c == 0) cnt2[r3] = 1.0f;
  }
  {
    float s = v * v;
    for (int off = 32; off > 0; off >>= 1) s += __shfl_down(s, off, 64);
    __shared__ float p[4];
    __shared__ float ns[2];
    int w = threadIdx.x >> 6;
    if ((threadIdx.x & 63) == 0) p[w] = s;
    __syncthreads();
    if ((threadIdx.x & 127) == 0) {
      float n = sqrtf(p[w] + p[w + 1]);
      nrm[row] = n;
      ns[threadIdx.x >> 7] = n;
    }
    __syncthreads();
    if (ext != nullptr) {
      float n = ns[threadIdx.x >> 7];
      ext[(size_t)row * 128 + c] = (_Float16)(v / n);
    }
  }
}

// --- 1x1 conv (128x128) + BN + SiLU, with fused cnt2-divide (finalize m2) ---
__global__ __launch_bounds__(256) void conv_bn_silu_kernel(
    const float* __restrict__ xf3, const float* __restrict__ cnt2,
    const float* __restrict__ w, const float* __restrict__ gamma,
    const float* __restrict__ beta, const float* __restrict__ mean,
    const float* __restrict__ var, float* __restrict__ out) {
  __shared__ float X[64][132];
  __shared__ float Wt[128][68];
  const int b = blockIdx.x & 7, p0 = (blockIdx.x >> 3) * 64;
  const int tid = threadIdx.x, lane = tid & 63, q = tid >> 6;
  {
    const float cn = cnt2[(size_t)b * 1024 + p0 + lane];
    const float* row = xf3 + ((size_t)b * 1024 + p0 + lane) * NC;
    for (int cc = 0; cc < 8; ++cc) {
      int c = q * 32 + cc * 4;
      float4 v = *(const float4*)&row[c];
      X[lane][c + 0] = v.x / cn;
      X[lane][c + 1] = v.y / cn;
      X[lane][c + 2] = v.z / cn;
      X[lane][c + 3] = v.w / cn;
    }
  }
  const int ti = tid >> 4, tj = tid & 15;
  const int i4 = ti * 4, j4 = tj * 4;
  for (int ot = 0; ot < 2; ++ot) {
    __syncthreads();
    {
      const float* row = w + (size_t)(ot * 64 + lane) * NC;
      for (int cc = 0; cc < 8; ++cc) {
        int c = q * 32 + cc * 4;
        float4 v = *(const float4*)&row[c];
        Wt[c + 0][lane] = v.x;
        Wt[c + 1][lane] = v.y;
        Wt[c + 2][lane] = v.z;
        Wt[c + 3][lane] = v.w;
      }
    }
    __syncthreads();
    float acc[4][4];
#pragma unroll
    for (int ii = 0; ii < 4; ++ii)
#pragma unroll
      for (int jj = 0; jj < 4; ++jj) acc[ii][jj] = 0.f;

    for (int k = 0; k < NC; k += 4) {
      float4 a0 = *(const float4*)&X[i4 + 0][k];
      float4 a1 = *(const float4*)&X[i4 + 1][k];
      float4 a2 = *(const float4*)&X[i4 + 2][k];
      float4 a3 = *(const float4*)&X[i4 + 3][k];
      float4 b0 = *(const float4*)&Wt[k + 0][j4];
      float4 b1 = *(const float4*)&Wt[k + 1][j4];
      float4 b2 = *(const float4*)&Wt[k + 2][j4];
      float4 b3 = *(const float4*)&Wt[k + 3][j4];
#define FMA16(AX, BV)                                                     \
  acc[0][0] += a0.AX * BV.x; acc[0][1] += a0.AX * BV.y;                   \
  acc[0][2] += a0.AX * BV.z; acc[0][3] += a0.AX * BV.w;                   \
  acc[1][0] += a1.AX * BV.x; acc[1][1] += a1.AX * BV.y;                   \
  acc[1][2] += a1.AX * BV.z; acc[1][3] += a1.AX * BV.w;                   \
  acc[2][0] += a2.AX * BV.x; acc[2][1] += a2.AX * BV.y;                   \
  acc[2][2] += a2.AX * BV.z; acc[2][3] += a2.AX * BV.w;                   \
  acc[3][0] += a3.AX * BV.x; acc[3][1] += a3.AX * BV.y;                   \
  acc[3][2] += a3.AX * BV.z; acc[3][3] += a3.AX * BV.w;
      FMA16(x, b0)
      FMA16(y, b1)
      FMA16(z, b2)
      FMA16(w, b3)
#undef FMA16
    }

#pragma unroll
    for (int jj = 0; jj < 4; ++jj) {
      int o = ot * 64 + j4 + jj;
      float sc = gamma[o] / sqrtf(var[o] + 1e-5f);
      float mn = mean[o], bt = beta[o];
      float4 r;
      float z;
      z = (acc[0][jj] - mn) * sc + bt; r.x = z / (1.f + expf(-z));
      z = (acc[1][jj] - mn) * sc + bt; r.y = z / (1.f + expf(-z));
      z = (acc[2][jj] - mn) * sc + bt; r.z = z / (1.f + expf(-z));
      z = (acc[3][jj] - mn) * sc + bt; r.w = z / (1.f + expf(-z));
      *(float4*)&out[((size_t)(b * NC + o)) * 1024 + p0 + i4] = r;
    }
  }
}

extern "C" void kernel_launch(void* const* d_in, const int* in_sizes, int n_in,
                              void* d_out, int out_size, void* d_ws,
                              size_t ws_size, hipStream_t stream) {
  const float* x = (const float*)d_in[0];
  const float* swp = (const float*)d_in[1];
  const float* dwp = (const float*)d_in[2];
  const float* convw = (const float*)d_in[3];
  const float* gamma = (const float*)d_in[4];
  const float* beta = (const float*)d_in[5];
  const float* mean = (const float*)d_in[6];
  const float* var = (const float*)d_in[7];
  float* out = (float*)d_out;

  float* ws = (float*)d_ws;
  size_t o = 0;
  float* xf1 = ws + o;  o += (size_t)8 * 4096 * 128;  // reused as xf3
  float* nrm1 = ws + o; o += 8 * 4096;
  float* xf2 = ws + o;  o += (size_t)8 * 2048 * 128;
  float* nrm2 = ws + o; o += 8 * 2048;
  float* cnt1 = ws + o; o += 8 * 2048;
  float* cnt2 = ws + o; o += 8 * 1024;
  int* dst1 = (int*)(ws + o); o += 8 * 2048;        // fallback only
  int* dst2 = (int*)(ws + o); o += 8 * 1024;        // fallback only
  float* lut = ws + o;  o += 8192;                  // fallback only
  unsigned long long* pu1 = (unsigned long long*)(ws + o);
  o += (size_t)8 * 2048 * 64 * 2;                   // 16384 rows x 64 u64
  unsigned long long* pu2 = (unsigned long long*)(ws + o);
  o += (size_t)8 * 1024 * 32 * 2;                   // 8192 rows x 32 u64
  _Float16* ext1 = (_Float16*)(ws + o);
  _Float16* ext2 = ext1;  // ext1 dead after merge-1 candidate pass
  const size_t ext_floats = (size_t)8 * 4096 * 128 / 2;
  const bool mfma_ok = ws_size >= (o + ext_floats) * sizeof(float);
  float* xf3 = xf1;  // alias: xf1 dead (tkrscat1 done) before xf3 written
  // fallback pv/pj alias the (unused-in-fallback) pu regions
  float* pv1 = (float*)pu1;
  int* pj1 = (int*)(pv1 + 8 * 2048 * 8);
  float* pv2 = (float*)pu2;
  int* pj2 = (int*)(pv2 + 8 * 1024 * 8);

  // ---- merge 1: T=4096, H=2048, width=64 ----
  prep_kernel<<<512, 256, 0, stream>>>(x, xf1, nrm1, mfma_ok ? ext1 : nullptr,
                                       xf2, cnt1);
  if (mfma_ok) {
    argmax_mfma10_kernel<64, 4096, 2048, 32>
        <<<2048, 256, 0, stream>>>(ext1, swp, dwp, pu1);
    tkrscat_kernel<64, 4096, 2048, 64>
        <<<4096, 256, 0, stream>>>(pu1, xf1, nrm1, swp, dwp, xf2, cnt1);
  } else {
    lut_kernel<<<32, 256, 0, stream>>>(lut, dwp, 7939);
    argmax2_kernel<64, 4096, 2048, 128, 256>
        <<<dim3(16, 8, 8), 256, 0, stream>>>(xf1, nrm1, swp, lut, pv1, pj1);
    argreduce_kernel<<<64, 256, 0, stream>>>(pv1, pj1, dst1, 8 * 2048, 8);
    scatter_kernel<<<2048, 256, 0, stream>>>(xf1, dst1, xf2, cnt1, 2048, 4096);
  }
  finalize1_kernel<<<8192, 256, 0, stream>>>(xf2, cnt1, nrm2,
                                             mfma_ok ? ext2 : nullptr,
                                             xf3, cnt2);

  // ---- merge 2: T=2048, H=1024, width=int(sqrt(2048))=45 ----
  if (mfma_ok) {
    argmax_mfma10_kernel<45, 2048, 1024, 16>
        <<<512, 256, 0, stream>>>(ext2, swp, dwp, pu2);
    tkrscat_kernel<45, 2048, 1024, 32>
        <<<2048, 256, 0, stream>>>(pu2, xf2, nrm2, swp, dwp, xf3, cnt2);
  } else {
    argmax2_kernel<45, 2048, 1024, 64, 128>
        <<<dim3(16, 8, 8), 256, 0, stream>>>(xf2, nrm2, swp, lut, pv2, pj2);
    argreduce_kernel<<<32, 256, 0, stream>>>(pv2, pj2, dst2, 8 * 1024, 8);
    scatter_kernel<<<1024, 256, 0, stream>>>(xf2, dst2, xf3, cnt2, 1024, 2048);
  }

  // ---- 1x1 conv + BN + SiLU (divides by cnt2 on load) ----
  conv_bn_silu_kernel<<<128, 256, 0, stream>>>(
      xf3, cnt2, convw, gamma, beta, mean, var, out);
}

// Round 16
// 129.459 us; speedup vs baseline: 1.0844x; 1.0844x over previous
//
#include <hip/hip_runtime.h>
#include <math.h>

#define NB 8
#define NC 128

typedef _Float16 hf8 __attribute__((ext_vector_type(8)));
typedef _Float16 hf4 __attribute__((ext_vector_type(4)));
typedef float fx4 __attribute__((ext_vector_type(4)));

// ---------------- LUT: lut[d2] = dw * (1/(sqrt(d2)+1e-6)) (fallback only) ---
__global__ void lut_kernel(float* __restrict__ lut, const float* __restrict__ dwp,
                           int n) {
  int i = blockIdx.x * 256 + threadIdx.x;
  if (i < n) {
    float r = 1.0f / (sqrtf((float)i) + 1e-6f);
    lut[i] = dwp[0] * r;
  }
}

// ---- prep: x (B,C,4096) -> xf1, nrm1, ext1 (K=128 fp16 metric), xf2/cnt1 ---
__global__ void prep_kernel(const float* __restrict__ x, float* __restrict__ xf,
                            float* __restrict__ nrm, _Float16* __restrict__ ext,
                            float* __restrict__ xf2, float* __restrict__ cnt1) {
  __shared__ float tile[64][129];
  __shared__ float part[64][4];
  __shared__ float rn_s[64];
  const int bid = blockIdx.x;
  const int b = bid & 7;
  const int p0 = (bid >> 3) * 64;
  const int tid = threadIdx.x;
  const int lane = tid & 63;
  const int q = tid >> 6;
  for (int cc = 0; cc < 32; ++cc) {
    int c = q * 32 + cc;
    tile[lane][c] = x[((size_t)(b * NC + c)) * 4096 + p0 + lane];
  }
  __syncthreads();
  float s = 0.f;
  for (int cc = 0; cc < 32; ++cc) {
    float v = tile[lane][q * 32 + cc];
    s += v * v;
  }
  part[lane][q] = s;
  __syncthreads();
  if (tid < 64) {
    float n = sqrtf(part[tid][0] + part[tid][1] + part[tid][2] + part[tid][3]);
    nrm[b * 4096 + p0 + tid] = n;
    rn_s[tid] = n;
  }
  __syncthreads();
  for (int it = 0; it < 8; ++it) {
    int idx = it * 256 + tid;
    int r = idx >> 5, e = (idx & 31) * 4;
    float4 v = make_float4(tile[r][e], tile[r][e + 1], tile[r][e + 2], tile[r][e + 3]);
    size_t o = (((size_t)b * 4096 + p0 + r) << 7) + e;
    *(float4*)&xf[o] = v;
    int tok = p0 + r;
    if (tok >= 2048) {  // merge-1 accumulator init (replaces copy_init m1)
      size_t row2 = (size_t)b * 2048 + tok - 2048;
      *(float4*)&xf2[row2 * NC + e] = v;
      if (e == 0) cnt1[row2] = 1.0f;
    }
    if (ext != nullptr) {
      float n = rn_s[r];
      _Float16* rw = ext + ((size_t)b * 4096 + tok) * 128;
      hf4 hv = {(_Float16)(v.x / n), (_Float16)(v.y / n),
                (_Float16)(v.z / n), (_Float16)(v.w / n)};
      *(hf4*)&rw[e] = hv;
    }
  }
}

// ------ MFMA candidate kernel v9: K=128 plain fp16, round-10 structure ------
// (round-13 best-passing version, reverted from the round-14 hoist regression)
// Block: 4 waves, each wave = 64i x 64j. 4 blocks/CU (35KB LDS, 64 VGPR).
// 1D grid: b = bid&7 (batch->XCD), jb = (bid>>3)&(NJB-1), ib = (bid>>3)/NJB.
// Emits packed u64 top-2 per (row, 64-j chunk).
template <int WIDTH, int TT, int HH, int NJB>
__global__ __launch_bounds__(256, 4) void argmax_mfma9_kernel(
    const _Float16* __restrict__ ext, const float* __restrict__ swp,
    const float* __restrict__ dwp, unsigned long long* __restrict__ pu) {
  // staging row stride 152 (bank pattern == round-10's 280); full 64*280
  // halfs reserved so the u64 reduce reuse (34816 B) fits.
  __shared__ _Float16 Bt[64 * 280];
  const int bid = blockIdx.x;
  const int b = bid & 7;
  const int rr = bid >> 3;
  const int jb = rr & (NJB - 1);
  const int ib = rr / NJB;
  const int tid = threadIdx.x;
  const int w = tid >> 6, l = tid & 63;
  const int lg = l >> 4, lm = l & 15;
  const int ipan = ib * 256 + w * 64;
  const int j0 = jb * 64;
  const float sw = swp[0], dwv = dwp[0];
  const _Float16* extb = ext + (size_t)b * TT * 128;
  const _Float16* brow0 = extb + (size_t)(HH + j0) * 128;

  const _Float16* ap[4];
#pragma unroll
  for (int s = 0; s < 4; ++s)
    ap[s] = extb + (size_t)(ipan + s * 16 + lm) * 128 + lg * 8;

  // stage B tile once: 64 rows x 128 halfs (1024 float4)
  for (int f = tid; f < 64 * 16; f += 256) {
    int r = f >> 4, c = f & 15;
    *(float4*)&Bt[r * 152 + c * 8] =
        *(const float4*)&brow0[(size_t)r * 128 + c * 8];
  }
  __syncthreads();

  fx4 acc[4][4];
#pragma unroll
  for (int i4 = 0; i4 < 4; ++i4)
#pragma unroll
    for (int j4 = 0; j4 < 4; ++j4) acc[i4][j4] = 0.f;

#pragma unroll
  for (int kc = 0; kc < 4; ++kc) {
    hf8 af[4], bf[4];
#pragma unroll
    for (int s = 0; s < 4; ++s)
      af[s] = *(const hf8*)(ap[s] + kc * 32);
#pragma unroll
    for (int s = 0; s < 4; ++s)
      bf[s] = *(const hf8*)&Bt[(s * 16 + lm) * 152 + kc * 32 + lg * 8];
    __builtin_amdgcn_s_setprio(1);
#pragma unroll
    for (int j4 = 0; j4 < 4; ++j4)
#pragma unroll
      for (int i4 = 0; i4 < 4; ++i4)
        acc[i4][j4] = __builtin_amdgcn_mfma_f32_16x16x32_f16(
            af[i4], bf[j4], acc[i4][j4], 0, 0, 0);
    __builtin_amdgcn_s_setprio(0);
  }

  // ---- epilogue: per-lane first-max over its 4 cols, per row ----
  // C/D layout: row = lg*4 + reg (+i4*16), col = lm (+j4*16).
  int jr4[4], jc4[4];
#pragma unroll
  for (int j4 = 0; j4 < 4; ++j4) {
    int tj = HH + j0 + j4 * 16 + lm;
    jr4[j4] = tj / WIDTH;
    jc4[j4] = tj % WIDTH;
  }
  __syncthreads();  // all waves done reading Bt -> reuse as reduce buffer
  unsigned long long* rwv = (unsigned long long*)&Bt[0] + (size_t)w * 64 * 17;
#pragma unroll
  for (int i4 = 0; i4 < 4; ++i4) {
#pragma unroll
    for (int rg = 0; rg < 4; ++rg) {
      int il = i4 * 16 + lg * 4 + rg;
      int ti = ipan + il;
      int ir = ti / WIDTH, ic = ti % WIDTH;
      float bv = -1e30f;
      int bj = 0;
#pragma unroll
      for (int j4 = 0; j4 < 4; ++j4) {  // ascending j -> first-max kept
        int dr = ir - jr4[j4], dc = ic - jc4[j4];
        float d2 = (float)(dr * dr + dc * dc);
        float sc = sw * acc[i4][j4][rg] + dwv * __builtin_amdgcn_rsqf(d2);
        int gj = j0 + j4 * 16 + lm;
        if (sc > bv) { bv = sc; bj = gj; }
      }
      rwv[il * 17 + lm] =
          ((unsigned long long)__float_as_uint(bv + 1.0f) << 32) |
          (unsigned)(~(unsigned)bj);
    }
  }
  __syncthreads();
  // lane l owns row l: top-2 over 16 lane-maxima (u64 packed order)
  unsigned long long t1 = 0ull, t2 = 0ull;
#pragma unroll
  for (int c = 0; c < 16; ++c) {
    unsigned long long u = rwv[l * 17 + c];
    if (u > t1) { t2 = t1; t1 = u; }
    else if (u > t2) { t2 = u; }
  }
  size_t row = (size_t)b * HH + ipan + l;
  pu[row * (HH / 32) + jb * 2 + 0] = t1;
  pu[row * (HH / 32) + jb * 2 + 1] = t2;
}

// --- fused top-4 + exact fp32 refine + SCATTER: one wave per row ------------
template <int WIDTH, int TT, int HH, int NCH2>
__global__ __launch_bounds__(256) void tkrscat_kernel(
    const unsigned long long* __restrict__ pu, const float* __restrict__ xf,
    const float* __restrict__ nrm, const float* __restrict__ swp,
    const float* __restrict__ dwp, float* __restrict__ accbuf,
    float* __restrict__ cnt) {
  const int bid = blockIdx.x;
  const int bb = bid & 7;
  const int row = bb * HH + (bid >> 3) * 4 + (threadIdx.x >> 6);
  const int lane = threadIdx.x & 63;
  unsigned long long v = (lane < NCH2) ? pu[(size_t)row * NCH2 + lane] : 0ull;
  int candv[4];
#pragma unroll
  for (int t = 0; t < 4; ++t) {
    unsigned long long m = v;
#pragma unroll
    for (int off = 1; off < 64; off <<= 1) {
      unsigned long long o = __shfl_xor(m, off, 64);
      if (o > m) m = o;
    }
    candv[t] = (int)(~(unsigned)(m & 0xFFFFFFFFull));
    if (v == m) v = 0ull;  // packed u64 unique per j -> exact removal
  }
  const int half = lane >> 5, ln = lane & 31;
  const int b = row / HH, i = row - b * HH;
  const float sw = swp[0], dwv = dwp[0];
  const float na = nrm[b * TT + i];
  float4 araw = *(const float4*)&xf[((size_t)b * TT + i) * NC + ln * 4];
  float4 a4 = make_float4(araw.x / na, araw.y / na, araw.z / na, araw.w / na);
  const int ir = i / WIDTH, ic = i % WIDTH;
  float bv = -3.0e38f;
  int bj = 0x7fffffff;
#pragma unroll
  for (int c = 0; c < 4; c += 2) {
    int j = candv[c + half];
    float4 b4 = *(const float4*)&xf[((size_t)b * TT + HH + j) * NC + ln * 4];
    float p = a4.x * b4.x + a4.y * b4.y + a4.z * b4.z + a4.w * b4.w;
#pragma unroll
    for (int off = 1; off < 32; off <<= 1) p += __shfl_xor(p, off, 32);
    float nb = nrm[b * TT + HH + j];
    int tj = HH + j;
    int jr = tj / WIDTH;
    int dr = ir - jr, dc = ic - (tj - jr * WIDTH);
    float r = 1.0f / (sqrtf((float)(dr * dr + dc * dc)) + 1e-6f);
    float sc = sw * (p / nb) + dwv * r;
    if (sc > bv || (sc == bv && j < bj)) { bv = sc; bj = j; }
  }
  {
    float ov = __shfl_xor(bv, 32, 64);
    int oj = __shfl_xor(bj, 32, 64);
    if (ov > bv || (ov == bv && oj < bj)) { bv = ov; bj = oj; }
  }
  if (half == 0) {
    float* base = &accbuf[((size_t)b * HH + bj) * NC + ln * 4];
    atomicAdd(base + 0, araw.x);
    atomicAdd(base + 1, araw.y);
    atomicAdd(base + 2, araw.z);
    atomicAdd(base + 3, araw.w);
    if (ln == 0) atomicAdd(&cnt[(size_t)b * HH + bj], 1.0f);
  }
}

// ---------------- FALLBACK fp32 path (round-1 structure, proven) ------------
template <int WIDTH, int TT, int HH, int IT, int JC>
__global__ __launch_bounds__(256, 4) void argmax2_kernel(
    const float* __restrict__ xf, const float* __restrict__ nrm,
    const float* __restrict__ swp, const float* __restrict__ lut,
    float* __restrict__ pval, int* __restrict__ pidx) {
  constexpr int MI = IT / 16;
  constexpr int NTILE = JC / 128;
  __shared__ float At[32][IT + 4];
  __shared__ float Bt[32][132];
  __shared__ int ico[2][IT];
  __shared__ int jco[2][JC];

  const int b = blockIdx.z;
  const int it0 = blockIdx.x * IT;
  const int jb = blockIdx.y;
  const int j0g = jb * JC;
  const int tid = threadIdx.x;

  for (int t = tid; t < IT; t += 256) {
    int tok = it0 + t;
    ico[0][t] = tok / WIDTH;
    ico[1][t] = tok % WIDTH;
  }
  for (int t = tid; t < JC; t += 256) {
    int tok = HH + j0g + t;
    jco[0][t] = tok / WIDTH;
    jco[1][t] = tok % WIDTH;
  }
  const float sw = swp[0];
  const float* srcb = xf + (size_t)b * TT * NC;

  const int ty = tid >> 4, tx = tid & 15;
  const int i0l = ty * MI;
  const int j0l = tx * 8;

  float best[MI];
  int bidx[MI];
#pragma unroll
  for (int ii = 0; ii < MI; ++ii) { best[ii] = -1e30f; bidx[ii] = 0; }

  for (int jt = 0; jt < NTILE; ++jt) {
    float acc[MI][8];
#pragma unroll
    for (int ii = 0; ii < MI; ++ii)
#pragma unroll
      for (int jj = 0; jj < 8; ++jj) acc[ii][jj] = 0.f;

    for (int kc = 0; kc < 4; ++kc) {
      __syncthreads();
#pragma unroll
      for (int p = 0; p < IT / 32; ++p) {
        int f = p * 256 + tid;
        int r = f >> 3, kq = (f & 7) * 4;
        const float* row = srcb + (size_t)(it0 + r) * NC + kc * 32 + kq;
        float4 v = *(const float4*)row;
        float n = nrm[b * TT + it0 + r];
        v.x /= n; v.y /= n; v.z /= n; v.w /= n;
        At[kq + 0][r] = v.x; At[kq + 1][r] = v.y;
        At[kq + 2][r] = v.z; At[kq + 3][r] = v.w;
      }
#pragma unroll
      for (int p = 0; p < 4; ++p) {
        int f = p * 256 + tid;
        int r = f >> 3, kq = (f & 7) * 4;
        int tok = HH + j0g + jt * 128 + r;
        const float* row = srcb + (size_t)tok * NC + kc * 32 + kq;
        float4 v = *(const float4*)row;
        float n = nrm[b * TT + tok];
        v.x /= n; v.y /= n; v.z /= n; v.w /= n;
        Bt[kq + 0][r] = v.x; Bt[kq + 1][r] = v.y;
        Bt[kq + 2][r] = v.z; Bt[kq + 3][r] = v.w;
      }
      __syncthreads();

#pragma unroll 4
      for (int k = 0; k < 32; ++k) {
        float a[MI], bb[8];
#pragma unroll
        for (int qv = 0; qv < MI / 4; ++qv)
          *(float4*)&a[qv * 4] = *(const float4*)&At[k][i0l + qv * 4];
        *(float4*)&bb[0] = *(const float4*)&Bt[k][j0l];
        *(float4*)&bb[4] = *(const float4*)&Bt[k][j0l + 4];
#pragma unroll
        for (int ii = 0; ii < MI; ++ii)
#pragma unroll
          for (int jj = 0; jj < 8; ++jj) acc[ii][jj] += a[ii] * bb[jj];
      }
    }

#pragma unroll
    for (int ii = 0; ii < MI; ++ii) {
      int ir = ico[0][i0l + ii], ic = ico[1][i0l + ii];
#pragma unroll
      for (int jj = 0; jj < 8; ++jj) {
        int jl = jt * 128 + j0l + jj;
        int dr = ir - jco[0][jl];
        int dc = ic - jco[1][jl];
        float sc = sw * acc[ii][jj] + lut[dr * dr + dc * dc];
        if (sc > best[ii]) {
          best[ii] = sc;
          bidx[ii] = j0g + jl;
        }
      }
    }
  }

  __syncthreads();
  float* rv = &At[0][0];
  int* rj = (int*)&Bt[0][0];
#pragma unroll
  for (int ii = 0; ii < MI; ++ii) {
    rv[(i0l + ii) * 17 + tx] = best[ii];
    rj[(i0l + ii) * 17 + tx] = bidx[ii];
  }
  __syncthreads();
  if (tid < IT) {
    float bv = rv[tid * 17];
    int bj = rj[tid * 17];
    for (int t = 1; t < 16; ++t) {
      float v = rv[tid * 17 + t];
      int j = rj[tid * 17 + t];
      if (v > bv || (v == bv && j < bj)) { bv = v; bj = j; }
    }
    int row = b * HH + it0 + tid;
    pval[(size_t)row * 8 + jb] = bv;
    pidx[(size_t)row * 8 + jb] = bj;
  }
}

__global__ void argreduce_kernel(const float* __restrict__ pv,
                                 const int* __restrict__ pj,
                                 int* __restrict__ dst, int nrows, int w) {
  int r = blockIdx.x * 256 + threadIdx.x;
  if (r >= nrows) return;
  const float* vv = pv + (size_t)r * w;
  const int* jj = pj + (size_t)r * w;
  float bv = vv[0];
  int bj = jj[0];
  for (int t = 1; t < w; ++t) {
    float v = vv[t];
    int j = jj[t];
    if (v > bv || (v == bv && j < bj)) { bv = v; bj = j; }
  }
  dst[r] = bj;
}

// fallback scatter (uses precomputed dst)
__global__ void scatter_kernel(const float* __restrict__ src,
                               const int* __restrict__ dst,
                               float* __restrict__ accbuf,
                               float* __restrict__ cnt, int HH, int TT) {
  const int b = blockIdx.x & 7;
  size_t local = (size_t)(blockIdx.x >> 3) * 256 + threadIdx.x;
  if (local >= (size_t)HH * 32) return;
  int i = (int)(local >> 5);
  int e = (int)(local & 31) * 4;
  float4 v = *(const float4*)&src[((size_t)b * TT + i) * NC + e];
  int d = dst[(size_t)b * HH + i];
  float* base = &accbuf[((size_t)b * HH + d) * NC + e];
  atomicAdd(base + 0, v.x);
  atomicAdd(base + 1, v.y);
  atomicAdd(base + 2, v.z);
  atomicAdd(base + 3, v.w);
  if (e == 0) atomicAdd(&cnt[(size_t)b * HH + d], 1.0f);
}

// finalize merge-1: divide xf2 by cnt1, emit nrm2 (+ ext2 fp16 metric rows),
// AND init merge-2 accumulator: b-half rows (t>=1024) copied to xf3, cnt2=1.
__global__ void finalize1_kernel(float* __restrict__ buf,
                                 const float* __restrict__ cnt,
                                 float* __restrict__ nrm,
                                 _Float16* __restrict__ ext,
                                 float* __restrict__ xf3,
                                 float* __restrict__ cnt2) {
  const int b = blockIdx.x & 7;
  int row = b * 2048 + (blockIdx.x >> 3) * 2 + (threadIdx.x >> 7);
  int c = threadIdx.x & 127;
  float v = buf[(size_t)row * NC + c] / cnt[row];
  buf[(size_t)row * NC + c] = v;
  int t = row & 2047;
  if (t >= 1024) {  // merge-2 accumulator init (replaces copy_init m2)
    size_t r3 = (size_t)b * 1024 + t - 1024;
    xf3[r3 * NC + c] = v;
    if (c == 0) cnt2[r3] = 1.0f;
  }
  {
    float s = v * v;
    for (int off = 32; off > 0; off >>= 1) s += __shfl_down(s, off, 64);
    __shared__ float p[4];
    __shared__ float ns[2];
    int w = threadIdx.x >> 6;
    if ((threadIdx.x & 63) == 0) p[w] = s;
    __syncthreads();
    if ((threadIdx.x & 127) == 0) {
      float n = sqrtf(p[w] + p[w + 1]);
      nrm[row] = n;
      ns[threadIdx.x >> 7] = n;
    }
    __syncthreads();
    if (ext != nullptr) {
      float n = ns[threadIdx.x >> 7];
      ext[(size_t)row * 128 + c] = (_Float16)(v / n);
    }
  }
}

// --- 1x1 conv (128x128) + BN + SiLU, fused cnt2-divide, ot split over grid --
// 1D grid 256: b = bid&7, rest = bid>>3 (0..31): p0 = (rest>>1)*64, ot=rest&1.
__global__ __launch_bounds__(256) void conv_bn_silu_kernel(
    const float* __restrict__ xf3, const float* __restrict__ cnt2,
    const float* __restrict__ w, const float* __restrict__ gamma,
    const float* __restrict__ beta, const float* __restrict__ mean,
    const float* __restrict__ var, float* __restrict__ out) {
  __shared__ float X[64][132];
  __shared__ float Wt[128][68];
  const int b = blockIdx.x & 7;
  const int rest = blockIdx.x >> 3;
  const int p0 = (rest >> 1) * 64;
  const int ot = rest & 1;
  const int tid = threadIdx.x, lane = tid & 63, q = tid >> 6;
  {
    const float cn = cnt2[(size_t)b * 1024 + p0 + lane];
    const float* row = xf3 + ((size_t)b * 1024 + p0 + lane) * NC;
    for (int cc = 0; cc < 8; ++cc) {
      int c = q * 32 + cc * 4;
      float4 v = *(const float4*)&row[c];
      X[lane][c + 0] = v.x / cn;
      X[lane][c + 1] = v.y / cn;
      X[lane][c + 2] = v.z / cn;
      X[lane][c + 3] = v.w / cn;
    }
  }
  {
    const float* row = w + (size_t)(ot * 64 + lane) * NC;
    for (int cc = 0; cc < 8; ++cc) {
      int c = q * 32 + cc * 4;
      float4 v = *(const float4*)&row[c];
      Wt[c + 0][lane] = v.x;
      Wt[c + 1][lane] = v.y;
      Wt[c + 2][lane] = v.z;
      Wt[c + 3][lane] = v.w;
    }
  }
  __syncthreads();
  const int ti = tid >> 4, tj = tid & 15;
  const int i4 = ti * 4, j4 = tj * 4;
  float acc[4][4];
#pragma unroll
  for (int ii = 0; ii < 4; ++ii)
#pragma unroll
    for (int jj = 0; jj < 4; ++jj) acc[ii][jj] = 0.f;

  for (int k = 0; k < NC; k += 4) {
    float4 a0 = *(const float4*)&X[i4 + 0][k];
    float4 a1 = *(const float4*)&X[i4 + 1][k];
    float4 a2 = *(const float4*)&X[i4 + 2][k];
    float4 a3 = *(const float4*)&X[i4 + 3][k];
    float4 b0 = *(const float4*)&Wt[k + 0][j4];
    float4 b1 = *(const float4*)&Wt[k + 1][j4];
    float4 b2 = *(const float4*)&Wt[k + 2][j4];
    float4 b3 = *(const float4*)&Wt[k + 3][j4];
#define FMA16(AX, BV)                                                     \
  acc[0][0] += a0.AX * BV.x; acc[0][1] += a0.AX * BV.y;                   \
  acc[0][2] += a0.AX * BV.z; acc[0][3] += a0.AX * BV.w;                   \
  acc[1][0] += a1.AX * BV.x; acc[1][1] += a1.AX * BV.y;                   \
  acc[1][2] += a1.AX * BV.z; acc[1][3] += a1.AX * BV.w;                   \
  acc[2][0] += a2.AX * BV.x; acc[2][1] += a2.AX * BV.y;                   \
  acc[2][2] += a2.AX * BV.z; acc[2][3] += a2.AX * BV.w;                   \
  acc[3][0] += a3.AX * BV.x; acc[3][1] += a3.AX * BV.y;                   \
  acc[3][2] += a3.AX * BV.z; acc[3][3] += a3.AX * BV.w;
    FMA16(x, b0)
    FMA16(y, b1)
    FMA16(z, b2)
    FMA16(w, b3)
#undef FMA16
  }

#pragma unroll
  for (int jj = 0; jj < 4; ++jj) {
    int o = ot * 64 + j4 + jj;
    float sc = gamma[o] / sqrtf(var[o] + 1e-5f);
    float mn = mean[o], bt = beta[o];
    float4 r;
    float z;
    z = (acc[0][jj] - mn) * sc + bt; r.x = z / (1.f + expf(-z));
    z = (acc[1][jj] - mn) * sc + bt; r.y = z / (1.f + expf(-z));
    z = (acc[2][jj] - mn) * sc + bt; r.z = z / (1.f + expf(-z));
    z = (acc[3][jj] - mn) * sc + bt; r.w = z / (1.f + expf(-z));
    *(float4*)&out[((size_t)(b * NC + o)) * 1024 + p0 + i4] = r;
  }
}

extern "C" void kernel_launch(void* const* d_in, const int* in_sizes, int n_in,
                              void* d_out, int out_size, void* d_ws,
                              size_t ws_size, hipStream_t stream) {
  const float* x = (const float*)d_in[0];
  const float* swp = (const float*)d_in[1];
  const float* dwp = (const float*)d_in[2];
  const float* convw = (const float*)d_in[3];
  const float* gamma = (const float*)d_in[4];
  const float* beta = (const float*)d_in[5];
  const float* mean = (const float*)d_in[6];
  const float* var = (const float*)d_in[7];
  float* out = (float*)d_out;

  float* ws = (float*)d_ws;
  size_t o = 0;
  float* xf1 = ws + o;  o += (size_t)8 * 4096 * 128;  // reused as xf3
  float* nrm1 = ws + o; o += 8 * 4096;
  float* xf2 = ws + o;  o += (size_t)8 * 2048 * 128;
  float* nrm2 = ws + o; o += 8 * 2048;
  float* cnt1 = ws + o; o += 8 * 2048;
  float* cnt2 = ws + o; o += 8 * 1024;
  int* dst1 = (int*)(ws + o); o += 8 * 2048;        // fallback only
  int* dst2 = (int*)(ws + o); o += 8 * 1024;        // fallback only
  float* lut = ws + o;  o += 8192;                  // fallback only
  unsigned long long* pu1 = (unsigned long long*)(ws + o);
  o += (size_t)8 * 2048 * 64 * 2;                   // 16384 rows x 64 u64
  unsigned long long* pu2 = (unsigned long long*)(ws + o);
  o += (size_t)8 * 1024 * 32 * 2;                   // 8192 rows x 32 u64
  _Float16* ext1 = (_Float16*)(ws + o);
  _Float16* ext2 = ext1;  // ext1 dead after merge-1 candidate pass
  const size_t ext_floats = (size_t)8 * 4096 * 128 / 2;
  const bool mfma_ok = ws_size >= (o + ext_floats) * sizeof(float);
  float* xf3 = xf1;  // alias: xf1 dead (tkrscat1 done) before xf3 written
  // fallback pv/pj alias the (unused-in-fallback) pu regions
  float* pv1 = (float*)pu1;
  int* pj1 = (int*)(pv1 + 8 * 2048 * 8);
  float* pv2 = (float*)pu2;
  int* pj2 = (int*)(pv2 + 8 * 1024 * 8);

  // ---- merge 1: T=4096, H=2048, width=64 ----
  prep_kernel<<<512, 256, 0, stream>>>(x, xf1, nrm1, mfma_ok ? ext1 : nullptr,
                                       xf2, cnt1);
  if (mfma_ok) {
    argmax_mfma9_kernel<64, 4096, 2048, 32>
        <<<2048, 256, 0, stream>>>(ext1, swp, dwp, pu1);
    tkrscat_kernel<64, 4096, 2048, 64>
        <<<4096, 256, 0, stream>>>(pu1, xf1, nrm1, swp, dwp, xf2, cnt1);
  } else {
    lut_kernel<<<32, 256, 0, stream>>>(lut, dwp, 7939);
    argmax2_kernel<64, 4096, 2048, 128, 256>
        <<<dim3(16, 8, 8), 256, 0, stream>>>(xf1, nrm1, swp, lut, pv1, pj1);
    argreduce_kernel<<<64, 256, 0, stream>>>(pv1, pj1, dst1, 8 * 2048, 8);
    scatter_kernel<<<2048, 256, 0, stream>>>(xf1, dst1, xf2, cnt1, 2048, 4096);
  }
  finalize1_kernel<<<8192, 256, 0, stream>>>(xf2, cnt1, nrm2,
                                             mfma_ok ? ext2 : nullptr,
                                             xf3, cnt2);

  // ---- merge 2: T=2048, H=1024, width=int(sqrt(2048))=45 ----
  if (mfma_ok) {
    argmax_mfma9_kernel<45, 2048, 1024, 16>
        <<<512, 256, 0, stream>>>(ext2, swp, dwp, pu2);
    tkrscat_kernel<45, 2048, 1024, 32>
        <<<2048, 256, 0, stream>>>(pu2, xf2, nrm2, swp, dwp, xf3, cnt2);
  } else {
    argmax2_kernel<45, 2048, 1024, 64, 128>
        <<<dim3(16, 8, 8), 256, 0, stream>>>(xf2, nrm2, swp, lut, pv2, pj2);
    argreduce_kernel<<<32, 256, 0, stream>>>(pv2, pj2, dst2, 8 * 1024, 8);
    scatter_kernel<<<1024, 256, 0, stream>>>(xf2, dst2, xf3, cnt2, 1024, 2048);
  }

  // ---- 1x1 conv + BN + SiLU (divides by cnt2 on load; ot split over grid) --
  conv_bn_silu_kernel<<<256, 256, 0, stream>>>(
      xf3, cnt2, convw, gamma, beta, mean, var, out);
}

// Round 17
// 128.382 us; speedup vs baseline: 1.0935x; 1.0084x over previous
//
#include <hip/hip_runtime.h>
#include <math.h>

#define NB 8
#define NC 128

typedef _Float16 hf8 __attribute__((ext_vector_type(8)));
typedef _Float16 hf4 __attribute__((ext_vector_type(4)));
typedef float fx4 __attribute__((ext_vector_type(4)));

// ---------------- LUT: lut[d2] = dw * (1/(sqrt(d2)+1e-6)) (fallback only) ---
__global__ void lut_kernel(float* __restrict__ lut, const float* __restrict__ dwp,
                           int n) {
  int i = blockIdx.x * 256 + threadIdx.x;
  if (i < n) {
    float r = 1.0f / (sqrtf((float)i) + 1e-6f);
    lut[i] = dwp[0] * r;
  }
}

// ---- prep: x (B,C,4096) -> xf1, nrm1, ext1 (K=128 fp16 metric), xf2/cnt1 ---
// x loads vectorized: float4 along spatial (full 1KiB/wave coalescing);
// LDS transpose-write is 2-way banked (free).
__global__ void prep_kernel(const float* __restrict__ x, float* __restrict__ xf,
                            float* __restrict__ nrm, _Float16* __restrict__ ext,
                            float* __restrict__ xf2, float* __restrict__ cnt1) {
  __shared__ float tile[64][129];
  __shared__ float part[64][4];
  __shared__ float rn_s[64];
  const int bid = blockIdx.x;
  const int b = bid & 7;
  const int p0 = (bid >> 3) * 64;
  const int tid = threadIdx.x;
  const int lane = tid & 63;
  const int q = tid >> 6;
  {
    const int ch = tid >> 4;           // 0..15 (channel within pass)
    const int ps = (tid & 15) * 4;     // spatial pos within 64-panel
    for (int it = 0; it < 8; ++it) {
      int c = it * 16 + ch;
      float4 v = *(const float4*)&x[((size_t)(b * NC + c)) * 4096 + p0 + ps];
      tile[ps + 0][c] = v.x;
      tile[ps + 1][c] = v.y;
      tile[ps + 2][c] = v.z;
      tile[ps + 3][c] = v.w;
    }
  }
  __syncthreads();
  float s = 0.f;
  for (int cc = 0; cc < 32; ++cc) {
    float v = tile[lane][q * 32 + cc];
    s += v * v;
  }
  part[lane][q] = s;
  __syncthreads();
  if (tid < 64) {
    float n = sqrtf(part[tid][0] + part[tid][1] + part[tid][2] + part[tid][3]);
    nrm[b * 4096 + p0 + tid] = n;
    rn_s[tid] = n;
  }
  __syncthreads();
  for (int it = 0; it < 8; ++it) {
    int idx = it * 256 + tid;
    int r = idx >> 5, e = (idx & 31) * 4;
    float4 v = make_float4(tile[r][e], tile[r][e + 1], tile[r][e + 2], tile[r][e + 3]);
    size_t o = (((size_t)b * 4096 + p0 + r) << 7) + e;
    *(float4*)&xf[o] = v;
    int tok = p0 + r;
    if (tok >= 2048) {  // merge-1 accumulator init (replaces copy_init m1)
      size_t row2 = (size_t)b * 2048 + tok - 2048;
      *(float4*)&xf2[row2 * NC + e] = v;
      if (e == 0) cnt1[row2] = 1.0f;
    }
    if (ext != nullptr) {
      float n = rn_s[r];
      _Float16* rw = ext + ((size_t)b * 4096 + tok) * 128;
      hf4 hv = {(_Float16)(v.x / n), (_Float16)(v.y / n),
                (_Float16)(v.z / n), (_Float16)(v.w / n)};
      *(hf4*)&rw[e] = hv;
    }
  }
}

// ------ MFMA candidate kernel v9: K=128 plain fp16 (round-13/15 proven) -----
// Block: 4 waves, each wave = 64i x 64j. 4 blocks/CU (35KB LDS, 64 VGPR).
// 1D grid: b = bid&7 (batch->XCD), jb = (bid>>3)&(NJB-1), ib = (bid>>3)/NJB.
// Emits packed u64 top-2 per (row, 64-j chunk).
template <int WIDTH, int TT, int HH, int NJB>
__global__ __launch_bounds__(256, 4) void argmax_mfma9_kernel(
    const _Float16* __restrict__ ext, const float* __restrict__ swp,
    const float* __restrict__ dwp, unsigned long long* __restrict__ pu) {
  __shared__ _Float16 Bt[64 * 280];  // stride-152 staging; reduce reuse fits
  const int bid = blockIdx.x;
  const int b = bid & 7;
  const int rr = bid >> 3;
  const int jb = rr & (NJB - 1);
  const int ib = rr / NJB;
  const int tid = threadIdx.x;
  const int w = tid >> 6, l = tid & 63;
  const int lg = l >> 4, lm = l & 15;
  const int ipan = ib * 256 + w * 64;
  const int j0 = jb * 64;
  const float sw = swp[0], dwv = dwp[0];
  const _Float16* extb = ext + (size_t)b * TT * 128;
  const _Float16* brow0 = extb + (size_t)(HH + j0) * 128;

  const _Float16* ap[4];
#pragma unroll
  for (int s = 0; s < 4; ++s)
    ap[s] = extb + (size_t)(ipan + s * 16 + lm) * 128 + lg * 8;

  // stage B tile once: 64 rows x 128 halfs (1024 float4)
  for (int f = tid; f < 64 * 16; f += 256) {
    int r = f >> 4, c = f & 15;
    *(float4*)&Bt[r * 152 + c * 8] =
        *(const float4*)&brow0[(size_t)r * 128 + c * 8];
  }
  __syncthreads();

  fx4 acc[4][4];
#pragma unroll
  for (int i4 = 0; i4 < 4; ++i4)
#pragma unroll
    for (int j4 = 0; j4 < 4; ++j4) acc[i4][j4] = 0.f;

#pragma unroll
  for (int kc = 0; kc < 4; ++kc) {
    hf8 af[4], bf[4];
#pragma unroll
    for (int s = 0; s < 4; ++s)
      af[s] = *(const hf8*)(ap[s] + kc * 32);
#pragma unroll
    for (int s = 0; s < 4; ++s)
      bf[s] = *(const hf8*)&Bt[(s * 16 + lm) * 152 + kc * 32 + lg * 8];
    __builtin_amdgcn_s_setprio(1);
#pragma unroll
    for (int j4 = 0; j4 < 4; ++j4)
#pragma unroll
      for (int i4 = 0; i4 < 4; ++i4)
        acc[i4][j4] = __builtin_amdgcn_mfma_f32_16x16x32_f16(
            af[i4], bf[j4], acc[i4][j4], 0, 0, 0);
    __builtin_amdgcn_s_setprio(0);
  }

  // ---- epilogue: per-lane first-max over its 4 cols, per row ----
  // C/D layout: row = lg*4 + reg (+i4*16), col = lm (+j4*16).
  int jr4[4], jc4[4];
#pragma unroll
  for (int j4 = 0; j4 < 4; ++j4) {
    int tj = HH + j0 + j4 * 16 + lm;
    jr4[j4] = tj / WIDTH;
    jc4[j4] = tj % WIDTH;
  }
  __syncthreads();  // all waves done reading Bt -> reuse as reduce buffer
  unsigned long long* rwv = (unsigned long long*)&Bt[0] + (size_t)w * 64 * 17;
#pragma unroll
  for (int i4 = 0; i4 < 4; ++i4) {
#pragma unroll
    for (int rg = 0; rg < 4; ++rg) {
      int il = i4 * 16 + lg * 4 + rg;
      int ti = ipan + il;
      int ir = ti / WIDTH, ic = ti % WIDTH;
      float bv = -1e30f;
      int bj = 0;
#pragma unroll
      for (int j4 = 0; j4 < 4; ++j4) {  // ascending j -> first-max kept
        int dr = ir - jr4[j4], dc = ic - jc4[j4];
        float d2 = (float)(dr * dr + dc * dc);
        float sc = sw * acc[i4][j4][rg] + dwv * __builtin_amdgcn_rsqf(d2);
        int gj = j0 + j4 * 16 + lm;
        if (sc > bv) { bv = sc; bj = gj; }
      }
      rwv[il * 17 + lm] =
          ((unsigned long long)__float_as_uint(bv + 1.0f) << 32) |
          (unsigned)(~(unsigned)bj);
    }
  }
  __syncthreads();
  // lane l owns row l: top-2 over 16 lane-maxima (u64 packed order)
  unsigned long long t1 = 0ull, t2 = 0ull;
#pragma unroll
  for (int c = 0; c < 16; ++c) {
    unsigned long long u = rwv[l * 17 + c];
    if (u > t1) { t2 = t1; t1 = u; }
    else if (u > t2) { t2 = u; }
  }
  size_t row = (size_t)b * HH + ipan + l;
  pu[row * (HH / 32) + jb * 2 + 0] = t1;
  pu[row * (HH / 32) + jb * 2 + 1] = t2;
}

// --- fused top-4 + exact fp32 refine + SCATTER: one wave per row ------------
template <int WIDTH, int TT, int HH, int NCH2>
__global__ __launch_bounds__(256) void tkrscat_kernel(
    const unsigned long long* __restrict__ pu, const float* __restrict__ xf,
    const float* __restrict__ nrm, const float* __restrict__ swp,
    const float* __restrict__ dwp, float* __restrict__ accbuf,
    float* __restrict__ cnt) {
  const int bid = blockIdx.x;
  const int bb = bid & 7;
  const int row = bb * HH + (bid >> 3) * 4 + (threadIdx.x >> 6);
  const int lane = threadIdx.x & 63;
  unsigned long long v = (lane < NCH2) ? pu[(size_t)row * NCH2 + lane] : 0ull;
  int candv[4];
#pragma unroll
  for (int t = 0; t < 4; ++t) {
    unsigned long long m = v;
#pragma unroll
    for (int off = 1; off < 64; off <<= 1) {
      unsigned long long o = __shfl_xor(m, off, 64);
      if (o > m) m = o;
    }
    candv[t] = (int)(~(unsigned)(m & 0xFFFFFFFFull));
    if (v == m) v = 0ull;  // packed u64 unique per j -> exact removal
  }
  const int half = lane >> 5, ln = lane & 31;
  const int b = row / HH, i = row - b * HH;
  const float sw = swp[0], dwv = dwp[0];
  const float na = nrm[b * TT + i];
  float4 araw = *(const float4*)&xf[((size_t)b * TT + i) * NC + ln * 4];
  float4 a4 = make_float4(araw.x / na, araw.y / na, araw.z / na, araw.w / na);
  const int ir = i / WIDTH, ic = i % WIDTH;
  float bv = -3.0e38f;
  int bj = 0x7fffffff;
#pragma unroll
  for (int c = 0; c < 4; c += 2) {
    int j = candv[c + half];
    float4 b4 = *(const float4*)&xf[((size_t)b * TT + HH + j) * NC + ln * 4];
    float p = a4.x * b4.x + a4.y * b4.y + a4.z * b4.z + a4.w * b4.w;
#pragma unroll
    for (int off = 1; off < 32; off <<= 1) p += __shfl_xor(p, off, 32);
    float nb = nrm[b * TT + HH + j];
    int tj = HH + j;
    int jr = tj / WIDTH;
    int dr = ir - jr, dc = ic - (tj - jr * WIDTH);
    float r = 1.0f / (sqrtf((float)(dr * dr + dc * dc)) + 1e-6f);
    float sc = sw * (p / nb) + dwv * r;
    if (sc > bv || (sc == bv && j < bj)) { bv = sc; bj = j; }
  }
  {
    float ov = __shfl_xor(bv, 32, 64);
    int oj = __shfl_xor(bj, 32, 64);
    if (ov > bv || (ov == bv && oj < bj)) { bv = ov; bj = oj; }
  }
  if (half == 0) {
    float* base = &accbuf[((size_t)b * HH + bj) * NC + ln * 4];
    atomicAdd(base + 0, araw.x);
    atomicAdd(base + 1, araw.y);
    atomicAdd(base + 2, araw.z);
    atomicAdd(base + 3, araw.w);
    if (ln == 0) atomicAdd(&cnt[(size_t)b * HH + bj], 1.0f);
  }
}

// ---------------- FALLBACK fp32 path (round-1 structure, proven) ------------
template <int WIDTH, int TT, int HH, int IT, int JC>
__global__ __launch_bounds__(256, 4) void argmax2_kernel(
    const float* __restrict__ xf, const float* __restrict__ nrm,
    const float* __restrict__ swp, const float* __restrict__ lut,
    float* __restrict__ pval, int* __restrict__ pidx) {
  constexpr int MI = IT / 16;
  constexpr int NTILE = JC / 128;
  __shared__ float At[32][IT + 4];
  __shared__ float Bt[32][132];
  __shared__ int ico[2][IT];
  __shared__ int jco[2][JC];

  const int b = blockIdx.z;
  const int it0 = blockIdx.x * IT;
  const int jb = blockIdx.y;
  const int j0g = jb * JC;
  const int tid = threadIdx.x;

  for (int t = tid; t < IT; t += 256) {
    int tok = it0 + t;
    ico[0][t] = tok / WIDTH;
    ico[1][t] = tok % WIDTH;
  }
  for (int t = tid; t < JC; t += 256) {
    int tok = HH + j0g + t;
    jco[0][t] = tok / WIDTH;
    jco[1][t] = tok % WIDTH;
  }
  const float sw = swp[0];
  const float* srcb = xf + (size_t)b * TT * NC;

  const int ty = tid >> 4, tx = tid & 15;
  const int i0l = ty * MI;
  const int j0l = tx * 8;

  float best[MI];
  int bidx[MI];
#pragma unroll
  for (int ii = 0; ii < MI; ++ii) { best[ii] = -1e30f; bidx[ii] = 0; }

  for (int jt = 0; jt < NTILE; ++jt) {
    float acc[MI][8];
#pragma unroll
    for (int ii = 0; ii < MI; ++ii)
#pragma unroll
      for (int jj = 0; jj < 8; ++jj) acc[ii][jj] = 0.f;

    for (int kc = 0; kc < 4; ++kc) {
      __syncthreads();
#pragma unroll
      for (int p = 0; p < IT / 32; ++p) {
        int f = p * 256 + tid;
        int r = f >> 3, kq = (f & 7) * 4;
        const float* row = srcb + (size_t)(it0 + r) * NC + kc * 32 + kq;
        float4 v = *(const float4*)row;
        float n = nrm[b * TT + it0 + r];
        v.x /= n; v.y /= n; v.z /= n; v.w /= n;
        At[kq + 0][r] = v.x; At[kq + 1][r] = v.y;
        At[kq + 2][r] = v.z; At[kq + 3][r] = v.w;
      }
#pragma unroll
      for (int p = 0; p < 4; ++p) {
        int f = p * 256 + tid;
        int r = f >> 3, kq = (f & 7) * 4;
        int tok = HH + j0g + jt * 128 + r;
        const float* row = srcb + (size_t)tok * NC + kc * 32 + kq;
        float4 v = *(const float4*)row;
        float n = nrm[b * TT + tok];
        v.x /= n; v.y /= n; v.z /= n; v.w /= n;
        Bt[kq + 0][r] = v.x; Bt[kq + 1][r] = v.y;
        Bt[kq + 2][r] = v.z; Bt[kq + 3][r] = v.w;
      }
      __syncthreads();

#pragma unroll 4
      for (int k = 0; k < 32; ++k) {
        float a[MI], bb[8];
#pragma unroll
        for (int qv = 0; qv < MI / 4; ++qv)
          *(float4*)&a[qv * 4] = *(const float4*)&At[k][i0l + qv * 4];
        *(float4*)&bb[0] = *(const float4*)&Bt[k][j0l];
        *(float4*)&bb[4] = *(const float4*)&Bt[k][j0l + 4];
#pragma unroll
        for (int ii = 0; ii < MI; ++ii)
#pragma unroll
          for (int jj = 0; jj < 8; ++jj) acc[ii][jj] += a[ii] * bb[jj];
      }
    }

#pragma unroll
    for (int ii = 0; ii < MI; ++ii) {
      int ir = ico[0][i0l + ii], ic = ico[1][i0l + ii];
#pragma unroll
      for (int jj = 0; jj < 8; ++jj) {
        int jl = jt * 128 + j0l + jj;
        int dr = ir - jco[0][jl];
        int dc = ic - jco[1][jl];
        float sc = sw * acc[ii][jj] + lut[dr * dr + dc * dc];
        if (sc > best[ii]) {
          best[ii] = sc;
          bidx[ii] = j0g + jl;
        }
      }
    }
  }

  __syncthreads();
  float* rv = &At[0][0];
  int* rj = (int*)&Bt[0][0];
#pragma unroll
  for (int ii = 0; ii < MI; ++ii) {
    rv[(i0l + ii) * 17 + tx] = best[ii];
    rj[(i0l + ii) * 17 + tx] = bidx[ii];
  }
  __syncthreads();
  if (tid < IT) {
    float bv = rv[tid * 17];
    int bj = rj[tid * 17];
    for (int t = 1; t < 16; ++t) {
      float v = rv[tid * 17 + t];
      int j = rj[tid * 17 + t];
      if (v > bv || (v == bv && j < bj)) { bv = v; bj = j; }
    }
    int row = b * HH + it0 + tid;
    pval[(size_t)row * 8 + jb] = bv;
    pidx[(size_t)row * 8 + jb] = bj;
  }
}

__global__ void argreduce_kernel(const float* __restrict__ pv,
                                 const int* __restrict__ pj,
                                 int* __restrict__ dst, int nrows, int w) {
  int r = blockIdx.x * 256 + threadIdx.x;
  if (r >= nrows) return;
  const float* vv = pv + (size_t)r * w;
  const int* jj = pj + (size_t)r * w;
  float bv = vv[0];
  int bj = jj[0];
  for (int t = 1; t < w; ++t) {
    float v = vv[t];
    int j = jj[t];
    if (v > bv || (v == bv && j < bj)) { bv = v; bj = j; }
  }
  dst[r] = bj;
}

// fallback scatter (uses precomputed dst)
__global__ void scatter_kernel(const float* __restrict__ src,
                               const int* __restrict__ dst,
                               float* __restrict__ accbuf,
                               float* __restrict__ cnt, int HH, int TT) {
  const int b = blockIdx.x & 7;
  size_t local = (size_t)(blockIdx.x >> 3) * 256 + threadIdx.x;
  if (local >= (size_t)HH * 32) return;
  int i = (int)(local >> 5);
  int e = (int)(local & 31) * 4;
  float4 v = *(const float4*)&src[((size_t)b * TT + i) * NC + e];
  int d = dst[(size_t)b * HH + i];
  float* base = &accbuf[((size_t)b * HH + d) * NC + e];
  atomicAdd(base + 0, v.x);
  atomicAdd(base + 1, v.y);
  atomicAdd(base + 2, v.z);
  atomicAdd(base + 3, v.w);
  if (e == 0) atomicAdd(&cnt[(size_t)b * HH + d], 1.0f);
}

// finalize merge-1: divide xf2 by cnt1, emit nrm2 (+ ext2 fp16 metric rows),
// AND init merge-2 accumulator: b-half rows (t>=1024) copied to xf3, cnt2=1.
__global__ void finalize1_kernel(float* __restrict__ buf,
                                 const float* __restrict__ cnt,
                                 float* __restrict__ nrm,
                                 _Float16* __restrict__ ext,
                                 float* __restrict__ xf3,
                                 float* __restrict__ cnt2) {
  const int b = blockIdx.x & 7;
  int row = b * 2048 + (blockIdx.x >> 3) * 2 + (threadIdx.x >> 7);
  int c = threadIdx.x & 127;
  float v = buf[(size_t)row * NC + c] / cnt[row];
  buf[(size_t)row * NC + c] = v;
  int t = row & 2047;
  if (t >= 1024) {  // merge-2 accumulator init (replaces copy_init m2)
    size_t r3 = (size_t)b * 1024 + t - 1024;
    xf3[r3 * NC + c] = v;
    if (c == 0) cnt2[r3] = 1.0f;
  }
  {
    float s = v * v;
    for (int off = 32; off > 0; off >>= 1) s += __shfl_down(s, off, 64);
    __shared__ float p[4];
    __shared__ float ns[2];
    int w = threadIdx.x >> 6;
    if ((threadIdx.x & 63) == 0) p[w] = s;
    __syncthreads();
    if ((threadIdx.x & 127) == 0) {
      float n = sqrtf(p[w] + p[w + 1]);
      nrm[row] = n;
      ns[threadIdx.x >> 7] = n;
    }
    __syncthreads();
    if (ext != nullptr) {
      float n = ns[threadIdx.x >> 7];
      ext[(size_t)row * 128 + c] = (_Float16)(v / n);
    }
  }
}

// --- 1x1 conv (128x128) + BN + SiLU, fused cnt2-divide, ot split over grid --
// 1D grid 256: b = bid&7, rest = bid>>3 (0..31): p0 = (rest>>1)*64, ot=rest&1.
__global__ __launch_bounds__(256) void conv_bn_silu_kernel(
    const float* __restrict__ xf3, const float* __restrict__ cnt2,
    const float* __restrict__ w, const float* __restrict__ gamma,
    const float* __restrict__ beta, const float* __restrict__ mean,
    const float* __restrict__ var, float* __restrict__ out) {
  __shared__ float X[64][132];
  __shared__ float Wt[128][68];
  const int b = blockIdx.x & 7;
  const int rest = blockIdx.x >> 3;
  const int p0 = (rest >> 1) * 64;
  const int ot = rest & 1;
  const int tid = threadIdx.x, lane = tid & 63, q = tid >> 6;
  {
    const float cn = cnt2[(size_t)b * 1024 + p0 + lane];
    const float* row = xf3 + ((size_t)b * 1024 + p0 + lane) * NC;
    for (int cc = 0; cc < 8; ++cc) {
      int c = q * 32 + cc * 4;
      float4 v = *(const float4*)&row[c];
      X[lane][c + 0] = v.x / cn;
      X[lane][c + 1] = v.y / cn;
      X[lane][c + 2] = v.z / cn;
      X[lane][c + 3] = v.w / cn;
    }
  }
  {
    const float* row = w + (size_t)(ot * 64 + lane) * NC;
    for (int cc = 0; cc < 8; ++cc) {
      int c = q * 32 + cc * 4;
      float4 v = *(const float4*)&row[c];
      Wt[c + 0][lane] = v.x;
      Wt[c + 1][lane] = v.y;
      Wt[c + 2][lane] = v.z;
      Wt[c + 3][lane] = v.w;
    }
  }
  __syncthreads();
  const int ti = tid >> 4, tj = tid & 15;
  const int i4 = ti * 4, j4 = tj * 4;
  float acc[4][4];
#pragma unroll
  for (int ii = 0; ii < 4; ++ii)
#pragma unroll
    for (int jj = 0; jj < 4; ++jj) acc[ii][jj] = 0.f;

  for (int k = 0; k < NC; k += 4) {
    float4 a0 = *(const float4*)&X[i4 + 0][k];
    float4 a1 = *(const float4*)&X[i4 + 1][k];
    float4 a2 = *(const float4*)&X[i4 + 2][k];
    float4 a3 = *(const float4*)&X[i4 + 3][k];
    float4 b0 = *(const float4*)&Wt[k + 0][j4];
    float4 b1 = *(const float4*)&Wt[k + 1][j4];
    float4 b2 = *(const float4*)&Wt[k + 2][j4];
    float4 b3 = *(const float4*)&Wt[k + 3][j4];
#define FMA16(AX, BV)                                                     \
  acc[0][0] += a0.AX * BV.x; acc[0][1] += a0.AX * BV.y;                   \
  acc[0][2] += a0.AX * BV.z; acc[0][3] += a0.AX * BV.w;                   \
  acc[1][0] += a1.AX * BV.x; acc[1][1] += a1.AX * BV.y;                   \
  acc[1][2] += a1.AX * BV.z; acc[1][3] += a1.AX * BV.w;                   \
  acc[2][0] += a2.AX * BV.x; acc[2][1] += a2.AX * BV.y;                   \
  acc[2][2] += a2.AX * BV.z; acc[2][3] += a2.AX * BV.w;                   \
  acc[3][0] += a3.AX * BV.x; acc[3][1] += a3.AX * BV.y;                   \
  acc[3][2] += a3.AX * BV.z; acc[3][3] += a3.AX * BV.w;
    FMA16(x, b0)
    FMA16(y, b1)
    FMA16(z, b2)
    FMA16(w, b3)
#undef FMA16
  }

#pragma unroll
  for (int jj = 0; jj < 4; ++jj) {
    int o = ot * 64 + j4 + jj;
    float sc = gamma[o] / sqrtf(var[o] + 1e-5f);
    float mn = mean[o], bt = beta[o];
    float4 r;
    float z;
    z = (acc[0][jj] - mn) * sc + bt; r.x = z / (1.f + expf(-z));
    z = (acc[1][jj] - mn) * sc + bt; r.y = z / (1.f + expf(-z));
    z = (acc[2][jj] - mn) * sc + bt; r.z = z / (1.f + expf(-z));
    z = (acc[3][jj] - mn) * sc + bt; r.w = z / (1.f + expf(-z));
    *(float4*)&out[((size_t)(b * NC + o)) * 1024 + p0 + i4] = r;
  }
}

extern "C" void kernel_launch(void* const* d_in, const int* in_sizes, int n_in,
                              void* d_out, int out_size, void* d_ws,
                              size_t ws_size, hipStream_t stream) {
  const float* x = (const float*)d_in[0];
  const float* swp = (const float*)d_in[1];
  const float* dwp = (const float*)d_in[2];
  const float* convw = (const float*)d_in[3];
  const float* gamma = (const float*)d_in[4];
  const float* beta = (const float*)d_in[5];
  const float* mean = (const float*)d_in[6];
  const float* var = (const float*)d_in[7];
  float* out = (float*)d_out;

  float* ws = (float*)d_ws;
  size_t o = 0;
  float* xf1 = ws + o;  o += (size_t)8 * 4096 * 128;  // reused as xf3
  float* nrm1 = ws + o; o += 8 * 4096;
  float* xf2 = ws + o;  o += (size_t)8 * 2048 * 128;
  float* nrm2 = ws + o; o += 8 * 2048;
  float* cnt1 = ws + o; o += 8 * 2048;
  float* cnt2 = ws + o; o += 8 * 1024;
  int* dst1 = (int*)(ws + o); o += 8 * 2048;        // fallback only
  int* dst2 = (int*)(ws + o); o += 8 * 1024;        // fallback only
  float* lut = ws + o;  o += 8192;                  // fallback only
  unsigned long long* pu1 = (unsigned long long*)(ws + o);
  o += (size_t)8 * 2048 * 64 * 2;                   // 16384 rows x 64 u64
  unsigned long long* pu2 = (unsigned long long*)(ws + o);
  o += (size_t)8 * 1024 * 32 * 2;                   // 8192 rows x 32 u64
  _Float16* ext1 = (_Float16*)(ws + o);
  _Float16* ext2 = ext1;  // ext1 dead after merge-1 candidate pass
  const size_t ext_floats = (size_t)8 * 4096 * 128 / 2;
  const bool mfma_ok = ws_size >= (o + ext_floats) * sizeof(float);
  float* xf3 = xf1;  // alias: xf1 dead (tkrscat1 done) before xf3 written
  // fallback pv/pj alias the (unused-in-fallback) pu regions
  float* pv1 = (float*)pu1;
  int* pj1 = (int*)(pv1 + 8 * 2048 * 8);
  float* pv2 = (float*)pu2;
  int* pj2 = (int*)(pv2 + 8 * 1024 * 8);

  // ---- merge 1: T=4096, H=2048, width=64 ----
  prep_kernel<<<512, 256, 0, stream>>>(x, xf1, nrm1, mfma_ok ? ext1 : nullptr,
                                       xf2, cnt1);
  if (mfma_ok) {
    argmax_mfma9_kernel<64, 4096, 2048, 32>
        <<<2048, 256, 0, stream>>>(ext1, swp, dwp, pu1);
    tkrscat_kernel<64, 4096, 2048, 64>
        <<<4096, 256, 0, stream>>>(pu1, xf1, nrm1, swp, dwp, xf2, cnt1);
  } else {
    lut_kernel<<<32, 256, 0, stream>>>(lut, dwp, 7939);
    argmax2_kernel<64, 4096, 2048, 128, 256>
        <<<dim3(16, 8, 8), 256, 0, stream>>>(xf1, nrm1, swp, lut, pv1, pj1);
    argreduce_kernel<<<64, 256, 0, stream>>>(pv1, pj1, dst1, 8 * 2048, 8);
    scatter_kernel<<<2048, 256, 0, stream>>>(xf1, dst1, xf2, cnt1, 2048, 4096);
  }
  finalize1_kernel<<<8192, 256, 0, stream>>>(xf2, cnt1, nrm2,
                                             mfma_ok ? ext2 : nullptr,
                                             xf3, cnt2);

  // ---- merge 2: T=2048, H=1024, width=int(sqrt(2048))=45 ----
  if (mfma_ok) {
    argmax_mfma9_kernel<45, 2048, 1024, 16>
        <<<512, 256, 0, stream>>>(ext2, swp, dwp, pu2);
    tkrscat_kernel<45, 2048, 1024, 32>
        <<<2048, 256, 0, stream>>>(pu2, xf2, nrm2, swp, dwp, xf3, cnt2);
  } else {
    argmax2_kernel<45, 2048, 1024, 64, 128>
        <<<dim3(16, 8, 8), 256, 0, stream>>>(xf2, nrm2, swp, lut, pv2, pj2);
    argreduce_kernel<<<32, 256, 0, stream>>>(pv2, pj2, dst2, 8 * 1024, 8);
    scatter_kernel<<<1024, 256, 0, stream>>>(xf2, dst2, xf3, cnt2, 1024, 2048);
  }

  // ---- 1x1 conv + BN + SiLU (divides by cnt2 on load; ot split over grid) --
  conv_bn_silu_kernel<<<256, 256, 0, stream>>>(
      xf3, cnt2, convw, gamma, beta, mean, var, out);
}